// Round 1
// 1743.797 us; speedup vs baseline: 1.1297x; 1.1297x over previous
//
#include <hip/hip_runtime.h>
#include <hip/hip_bf16.h>
#include <math.h>

// NODE_DIM=3, EMBED=16
#define ND 3
#define EM 16
#define NR 8          // dst ranges == XCD count (blockIdx % 8 ~ XCD id)
#define EPB 4096      // edges per block-chunk in ranged kernels (256 thr * 16)

__device__ __forceinline__ float sp(float x) {
    // jax.nn.softplus = max(x,0) + log1p(exp(-|x|))
    return fmaxf(x, 0.0f) + log1pf(expf(-fabsf(x)));
}

// Kernel 1: x0 = softplus(pos @ W_init + b_init); xwA = x0 @ W_g1. Zero cnt.
__global__ __launch_bounds__(256) void node_init(
    const float* __restrict__ pos,
    const float* __restrict__ W_init, const float* __restrict__ b_init,
    const float* __restrict__ W_g1,
    float* __restrict__ xw, int* __restrict__ cnt, int N)
{
    __shared__ float sWi[ND * EM];
    __shared__ float sbi[EM];
    __shared__ float sW1[EM * EM];
    int t = threadIdx.x;
    if (t < ND * EM) sWi[t] = W_init[t];
    if (t < EM)      sbi[t] = b_init[t];
    sW1[t] = W_g1[t];
    __syncthreads();

    int n = blockIdx.x * 256 + t;
    if (n >= N) return;

    float p0 = pos[3 * (size_t)n + 0];
    float p1 = pos[3 * (size_t)n + 1];
    float p2 = pos[3 * (size_t)n + 2];

    float x0[EM];
#pragma unroll
    for (int j = 0; j < EM; j++) {
        float h = fmaf(p0, sWi[0 * EM + j],
                  fmaf(p1, sWi[1 * EM + j],
                  fmaf(p2, sWi[2 * EM + j], sbi[j])));
        x0[j] = sp(h);
    }
    float o[EM];
#pragma unroll
    for (int k = 0; k < EM; k++) {
        float a = 0.0f;
#pragma unroll
        for (int j = 0; j < EM; j++) a = fmaf(x0[j], sW1[j * EM + k], a);
        o[k] = a;
    }
    float4* xo = (float4*)(xw + (size_t)n * EM);
#pragma unroll
    for (int q = 0; q < 4; q++)
        xo[q] = make_float4(o[4*q+0], o[4*q+1], o[4*q+2], o[4*q+3]);
    cnt[n] = 0;
}

// Kernel 2 (ranged): in-degree count. Block group g = blockIdx%8 handles dst
// range [lo, lo+len); groups stream the whole dst array (L3-resident), so
// each XCD's atomics land in a private 250KB window of cnt.
__global__ __launch_bounds__(256) void edge_count_r(
    const int* __restrict__ ei, int* __restrict__ cnt, int E, int N)
{
    int g = blockIdx.x & (NR - 1);
    int c = blockIdx.x / NR;
    int q = N / NR, r = N % NR;
    int lo  = g * q + (g < r ? g : r);
    int len = q + (g < r ? 1 : 0);
    const int* dp = ei + (size_t)E;
    int segbase = c * EPB;

    if ((E & 3) == 0) {
#pragma unroll
        for (int it = 0; it < 4; it++) {
            int e0 = segbase + it * 1024 + threadIdx.x * 4;
            if (e0 >= E) continue;
            int4 d4 = *(const int4*)(dp + e0);
            if ((unsigned)(d4.x - lo) < (unsigned)len) atomicAdd(&cnt[d4.x], 1);
            if ((unsigned)(d4.y - lo) < (unsigned)len) atomicAdd(&cnt[d4.y], 1);
            if ((unsigned)(d4.z - lo) < (unsigned)len) atomicAdd(&cnt[d4.z], 1);
            if ((unsigned)(d4.w - lo) < (unsigned)len) atomicAdd(&cnt[d4.w], 1);
        }
    } else {
        for (int it = 0; it < 16; it++) {
            int e = segbase + it * 256 + threadIdx.x;
            if (e < E) {
                int d = dp[e];
                if ((unsigned)(d - lo) < (unsigned)len) atomicAdd(&cnt[d], 1);
            }
        }
    }
}

// Kernel 3a: per-block (1024 nodes) partial sums of cnt.
__global__ __launch_bounds__(256) void scan_partial(
    const int* __restrict__ cnt, int* __restrict__ bsums, int N)
{
    __shared__ int sd[256];
    int t = threadIdx.x;
    int base = blockIdx.x * 1024 + t * 4;
    int s = 0;
#pragma unroll
    for (int i = 0; i < 4; i++) { int n = base + i; if (n < N) s += cnt[n]; }
    sd[t] = s;
    __syncthreads();
    for (int off = 128; off >= 1; off >>= 1) {
        if (t < off) sd[t] += sd[t + off];
        __syncthreads();
    }
    if (t == 0) bsums[blockIdx.x] = sd[0];
}

// Kernel 3b: exclusive scan of block sums in place (NB <= 1024).
__global__ __launch_bounds__(1024) void scan_blocksums(int* __restrict__ bsums, int NB)
{
    __shared__ int sd[1024];
    int t = threadIdx.x;
    int v = (t < NB) ? bsums[t] : 0;
    sd[t] = v;
    __syncthreads();
    for (int off = 1; off < 1024; off <<= 1) {
        int add = (t >= off) ? sd[t - off] : 0;
        __syncthreads();
        sd[t] += add;
        __syncthreads();
    }
    if (t < NB) bsums[t] = sd[t] - v;  // exclusive
}

// Kernel 3c: final rowptr + cursor init.
__global__ __launch_bounds__(256) void scan_final(
    const int* __restrict__ cnt, const int* __restrict__ bsums,
    int* __restrict__ rowptr, int* __restrict__ cursor, int N, int E)
{
    __shared__ int sd[256];
    int t = threadIdx.x;
    int n0 = blockIdx.x * 1024 + t * 4;
    int c[4];
#pragma unroll
    for (int i = 0; i < 4; i++) c[i] = (n0 + i < N) ? cnt[n0 + i] : 0;
    int mysum = c[0] + c[1] + c[2] + c[3];
    sd[t] = mysum;
    __syncthreads();
    for (int off = 1; off < 256; off <<= 1) {
        int add = (t >= off) ? sd[t - off] : 0;
        __syncthreads();
        sd[t] += add;
        __syncthreads();
    }
    int r = bsums[blockIdx.x] + sd[t] - mysum;
#pragma unroll
    for (int i = 0; i < 4; i++) {
        int n = n0 + i;
        if (n < N) { rowptr[n] = r; cursor[n] = r; r += c[i]; }
    }
    if (blockIdx.x == 0 && t == 0) rowptr[N] = E;
}

// Kernel 4 (ranged): scatter edge src ids into dst-sorted buckets.
// Block group g = blockIdx%8 (~XCD g) only fills dst range [lo, lo+len):
// all writes to one col cache line then come from a single XCD, so its L2
// merges the ~16 slot-writes into one line writeback instead of 16.
__global__ __launch_bounds__(256) void edge_fill_r(
    const int* __restrict__ ei, int* __restrict__ cursor,
    int* __restrict__ col, int E, int N)
{
    int g = blockIdx.x & (NR - 1);
    int c = blockIdx.x / NR;
    int q = N / NR, r = N % NR;
    int lo  = g * q + (g < r ? g : r);
    int len = q + (g < r ? 1 : 0);
    const int* dp = ei + (size_t)E;
    int segbase = c * EPB;

    if ((E & 3) == 0) {
#pragma unroll
        for (int it = 0; it < 4; it++) {
            int e0 = segbase + it * 1024 + threadIdx.x * 4;
            if (e0 >= E) continue;
            int4 d4 = *(const int4*)(dp + e0);
            bool a0 = (unsigned)(d4.x - lo) < (unsigned)len;
            bool a1 = (unsigned)(d4.y - lo) < (unsigned)len;
            bool a2 = (unsigned)(d4.z - lo) < (unsigned)len;
            bool a3 = (unsigned)(d4.w - lo) < (unsigned)len;
            if (a0 | a1 | a2 | a3) {
                int4 s4 = *(const int4*)(ei + e0);
                if (a0) { int slot = atomicAdd(&cursor[d4.x], 1); col[slot] = s4.x; }
                if (a1) { int slot = atomicAdd(&cursor[d4.y], 1); col[slot] = s4.y; }
                if (a2) { int slot = atomicAdd(&cursor[d4.z], 1); col[slot] = s4.z; }
                if (a3) { int slot = atomicAdd(&cursor[d4.w], 1); col[slot] = s4.w; }
            }
        }
    } else {
        for (int it = 0; it < 16; it++) {
            int e = segbase + it * 256 + threadIdx.x;
            if (e < E) {
                int d = dp[e];
                if ((unsigned)(d - lo) < (unsigned)len) {
                    int slot = atomicAdd(&cursor[d], 1);
                    col[slot] = ei[e];
                }
            }
        }
    }
}

// Kernel 5: weighted degree via gather; dinv = rsqrt(1 + sum_w).
// 16 lanes per node; lane j handles edges start+j, start+j+16, ...
__global__ __launch_bounds__(256) void deg_gather(
    const int* __restrict__ rowptr, const int* __restrict__ col,
    const float* __restrict__ pos, float* __restrict__ dinv, int N)
{
    int t = threadIdx.x;
    int lane = t & 15;
    int n = blockIdx.x * 16 + (t >> 4);
    if (n >= N) return;
    int start = rowptr[n], end = rowptr[n + 1];
    float px = pos[3 * (size_t)n + 0];
    float py = pos[3 * (size_t)n + 1];
    float pz = pos[3 * (size_t)n + 2];
    float sum = 0.0f;
    for (int j = start + lane; j < end; j += 16) {
        int s = col[j];
        float dx = px - pos[3 * (size_t)s + 0];
        float dy = py - pos[3 * (size_t)s + 1];
        float dz = pz - pos[3 * (size_t)s + 2];
        sum += sqrtf(fmaf(dx, dx, fmaf(dy, dy, dz * dz)));
    }
#pragma unroll
    for (int off = 8; off >= 1; off >>= 1) sum += __shfl_xor(sum, off, 64);
    if (lane == 0) dinv[n] = rsqrtf(1.0f + sum);
}

// Kernel 6 (x2): fused GCN-mean layer via gather.
// 16 lanes per node, lane = output channel. For each incident edge:
// nrm = dinv[src]*w*dinv[n]; acc += nrm * xin[src][c]. Then add self-loop
// dinv^2 * xin[n][c], divide by (deg_count+1), add bias, softplus.
// If mulW: out = x @ W (16x16) via LDS; else out = x.
__global__ __launch_bounds__(256) void gather_conv(
    const int* __restrict__ rowptr, const int* __restrict__ col,
    const float* __restrict__ pos, const float* __restrict__ dinv,
    const float* __restrict__ xin, const float* __restrict__ bconv,
    const float* __restrict__ W, float* __restrict__ xout, int N, int mulW)
{
    __shared__ float sW[EM * EM];
    __shared__ float lx[16][EM + 1];
    int t = threadIdx.x;
    sW[t] = W[t];
    int g = t >> 4, c = t & 15;
    int n = blockIdx.x * 16 + g;

    float x = 0.0f;
    if (n < N) {
        int start = rowptr[n], end = rowptr[n + 1];
        float di = dinv[n];
        float px = pos[3 * (size_t)n + 0];
        float py = pos[3 * (size_t)n + 1];
        float pz = pos[3 * (size_t)n + 2];
        float acc = 0.0f;
        for (int j = start; j < end; j++) {
            int s = col[j];
            float dx = px - pos[3 * (size_t)s + 0];
            float dy = py - pos[3 * (size_t)s + 1];
            float dz = pz - pos[3 * (size_t)s + 2];
            float w = sqrtf(fmaf(dx, dx, fmaf(dy, dy, dz * dz)));
            float nrm = dinv[s] * w * di;
            acc = fmaf(nrm, xin[(size_t)s * EM + c], acc);
        }
        acc = fmaf(di * di, xin[(size_t)n * EM + c], acc);  // self loop
        float rc = 1.0f / (float)(end - start + 1);
        x = sp(fmaf(acc, rc, bconv[c]));
    }
    __syncthreads();      // sW ready
    lx[g][c] = x;
    __syncthreads();
    if (n < N) {
        if (mulW) {
            float a = 0.0f;
#pragma unroll
            for (int j = 0; j < EM; j++) a = fmaf(lx[g][j], sW[j * EM + c], a);
            xout[(size_t)n * EM + c] = a;
        } else {
            xout[(size_t)n * EM + c] = x;
        }
    }
}

// Kernel 7: dense heads: y = sp(x2 @ Wp1 + bp1); out = (y @ Wp2 + bp2)/sig.
__global__ __launch_bounds__(256) void node_out(
    const float* __restrict__ W_p1, const float* __restrict__ b_p1,
    const float* __restrict__ W_p2, const float* __restrict__ b_p2,
    const float* __restrict__ sig, const float* __restrict__ x2arr,
    float* __restrict__ out, int N)
{
    __shared__ float sP1[EM * EM];
    __shared__ float sbp1[EM];
    __shared__ float sP2[EM * ND];
    __shared__ float sbp2[ND];
    int t = threadIdx.x;
    sP1[t] = W_p1[t];
    if (t < EM)      sbp1[t] = b_p1[t];
    if (t < EM * ND) sP2[t] = W_p2[t];
    if (t < ND)      sbp2[t] = b_p2[t];
    __syncthreads();

    int n = blockIdx.x * 256 + t;
    if (n >= N) return;

    const float4* xp = (const float4*)(x2arr + (size_t)n * EM);
    float x2[EM];
#pragma unroll
    for (int q = 0; q < 4; q++) {
        float4 xv = xp[q];
        x2[4*q+0] = xv.x; x2[4*q+1] = xv.y; x2[4*q+2] = xv.z; x2[4*q+3] = xv.w;
    }
    float y[EM];
#pragma unroll
    for (int k = 0; k < EM; k++) {
        float a = sbp1[k];
#pragma unroll
        for (int j = 0; j < EM; j++) a = fmaf(x2[j], sP1[j * EM + k], a);
        y[k] = sp(a);
    }
    float rs = 1.0f / sig[n];
#pragma unroll
    for (int ch = 0; ch < ND; ch++) {
        float a = sbp2[ch];
#pragma unroll
        for (int j = 0; j < EM; j++) a = fmaf(y[j], sP2[j * ND + ch], a);
        out[(size_t)n * ND + ch] = a * rs;
    }
}

extern "C" void kernel_launch(void* const* d_in, const int* in_sizes, int n_in,
                              void* d_out, int out_size, void* d_ws, size_t ws_size,
                              hipStream_t stream) {
    const float* pos    = (const float*)d_in[0];
    const float* sig    = (const float*)d_in[1];
    const int*   ei     = (const int*)d_in[2];
    const float* W_init = (const float*)d_in[4];
    const float* b_init = (const float*)d_in[5];
    const float* W_g1   = (const float*)d_in[6];
    const float* b_g1   = (const float*)d_in[7];
    const float* W_g2   = (const float*)d_in[8];
    const float* b_g2   = (const float*)d_in[9];
    const float* W_p1   = (const float*)d_in[10];
    const float* b_p1   = (const float*)d_in[11];
    const float* W_p2   = (const float*)d_in[12];
    const float* b_p2   = (const float*)d_in[13];
    float* out = (float*)d_out;

    int N = in_sizes[0] / ND;
    int E = in_sizes[2] / 2;
    size_t Ns = (size_t)N, Es = (size_t)E;

    // Workspace layout (4B elements):
    // rowptr[N+1] | cnt[N] | col[E] | bsums[1024] | dinv[N] | xwA[16N] | xwB[16N]
    // cursor aliases the start of xwB (dead before xwB is first written).
    int* rowptr = (int*)d_ws;
    int* cnt    = rowptr + (Ns + 1);
    int* col    = cnt + Ns;
    int* bsums  = col + Es;
    size_t off  = (Ns + 1) + Ns + Es + 1024;
    off = (off + 3) & ~(size_t)3;
    float* dinv = (float*)d_ws + off;
    size_t offA = off + Ns;
    offA = (offA + 3) & ~(size_t)3;
    float* xwA  = (float*)d_ws + offA;
    float* xwB  = xwA + Ns * EM;
    int* cursor = (int*)xwB;

    int nbN = (N + 255) / 256;
    int NBS = (N + 1023) / 1024;   // scan blocks (must be <= 1024)
    int nbG = (N + 15) / 16;       // 16 nodes per 256-thread block
    int nbEr = NR * ((E + EPB - 1) / EPB);  // ranged edge kernels

    node_init<<<nbN, 256, 0, stream>>>(pos, W_init, b_init, W_g1, xwA, cnt, N);
    edge_count_r<<<nbEr, 256, 0, stream>>>(ei, cnt, E, N);
    scan_partial<<<NBS, 256, 0, stream>>>(cnt, bsums, N);
    scan_blocksums<<<1, 1024, 0, stream>>>(bsums, NBS);
    scan_final<<<NBS, 256, 0, stream>>>(cnt, bsums, rowptr, cursor, N, E);
    edge_fill_r<<<nbEr, 256, 0, stream>>>(ei, cursor, col, E, N);
    deg_gather<<<nbG, 256, 0, stream>>>(rowptr, col, pos, dinv, N);
    gather_conv<<<nbG, 256, 0, stream>>>(rowptr, col, pos, dinv, xwA, b_g1, W_g2, xwB, N, 1);
    gather_conv<<<nbG, 256, 0, stream>>>(rowptr, col, pos, dinv, xwB, b_g2, W_g2, xwA, N, 0);
    node_out<<<nbN, 256, 0, stream>>>(W_p1, b_p1, W_p2, b_p2, sig, xwA, out, N);
}

// Round 2
// 1385.178 us; speedup vs baseline: 1.4222x; 1.2589x over previous
//
#include <hip/hip_runtime.h>
#include <hip/hip_bf16.h>
#include <math.h>

// NODE_DIM=3, EMBED=16
#define ND 3
#define EM 16
#define NR 8          // dst ranges == XCD count (blockIdx % 8 ~ XCD id)
#define EPB 4096      // edges per block-chunk in ranged kernels (256 thr * 16)

__device__ __forceinline__ float sp(float x) {
    // jax.nn.softplus = max(x,0) + log1p(exp(-|x|))
    return fmaxf(x, 0.0f) + log1pf(expf(-fabsf(x)));
}

// Kernel 1: x0 = softplus(pos @ W_init + b_init); xwA = x0 @ W_g1. Zero cnt.
__global__ __launch_bounds__(256) void node_init(
    const float* __restrict__ pos,
    const float* __restrict__ W_init, const float* __restrict__ b_init,
    const float* __restrict__ W_g1,
    float* __restrict__ xw, int* __restrict__ cnt, int N)
{
    __shared__ float sWi[ND * EM];
    __shared__ float sbi[EM];
    __shared__ float sW1[EM * EM];
    int t = threadIdx.x;
    if (t < ND * EM) sWi[t] = W_init[t];
    if (t < EM)      sbi[t] = b_init[t];
    sW1[t] = W_g1[t];
    __syncthreads();

    int n = blockIdx.x * 256 + t;
    if (n >= N) return;

    float p0 = pos[3 * (size_t)n + 0];
    float p1 = pos[3 * (size_t)n + 1];
    float p2 = pos[3 * (size_t)n + 2];

    float x0[EM];
#pragma unroll
    for (int j = 0; j < EM; j++) {
        float h = fmaf(p0, sWi[0 * EM + j],
                  fmaf(p1, sWi[1 * EM + j],
                  fmaf(p2, sWi[2 * EM + j], sbi[j])));
        x0[j] = sp(h);
    }
    float o[EM];
#pragma unroll
    for (int k = 0; k < EM; k++) {
        float a = 0.0f;
#pragma unroll
        for (int j = 0; j < EM; j++) a = fmaf(x0[j], sW1[j * EM + k], a);
        o[k] = a;
    }
    float4* xo = (float4*)(xw + (size_t)n * EM);
#pragma unroll
    for (int q = 0; q < 4; q++)
        xo[q] = make_float4(o[4*q+0], o[4*q+1], o[4*q+2], o[4*q+3]);
    cnt[n] = 0;
}

// Kernel 2 (ranged): in-degree count. Block group g = blockIdx%8 handles dst
// range [lo, lo+len); groups stream the whole dst array (L3-resident), so
// each XCD's atomics land in a private 250KB window of cnt.
__global__ __launch_bounds__(256) void edge_count_r(
    const int* __restrict__ ei, int* __restrict__ cnt, int E, int N)
{
    int g = blockIdx.x & (NR - 1);
    int c = blockIdx.x / NR;
    int q = N / NR, r = N % NR;
    int lo  = g * q + (g < r ? g : r);
    int len = q + (g < r ? 1 : 0);
    const int* dp = ei + (size_t)E;
    int segbase = c * EPB;

    if ((E & 3) == 0) {
#pragma unroll
        for (int it = 0; it < 4; it++) {
            int e0 = segbase + it * 1024 + threadIdx.x * 4;
            if (e0 >= E) continue;
            int4 d4 = *(const int4*)(dp + e0);
            if ((unsigned)(d4.x - lo) < (unsigned)len) atomicAdd(&cnt[d4.x], 1);
            if ((unsigned)(d4.y - lo) < (unsigned)len) atomicAdd(&cnt[d4.y], 1);
            if ((unsigned)(d4.z - lo) < (unsigned)len) atomicAdd(&cnt[d4.z], 1);
            if ((unsigned)(d4.w - lo) < (unsigned)len) atomicAdd(&cnt[d4.w], 1);
        }
    } else {
        for (int it = 0; it < 16; it++) {
            int e = segbase + it * 256 + threadIdx.x;
            if (e < E) {
                int d = dp[e];
                if ((unsigned)(d - lo) < (unsigned)len) atomicAdd(&cnt[d], 1);
            }
        }
    }
}

// Kernel 3a: per-block (1024 nodes) partial sums of cnt.
__global__ __launch_bounds__(256) void scan_partial(
    const int* __restrict__ cnt, int* __restrict__ bsums, int N)
{
    __shared__ int sd[256];
    int t = threadIdx.x;
    int base = blockIdx.x * 1024 + t * 4;
    int s = 0;
#pragma unroll
    for (int i = 0; i < 4; i++) { int n = base + i; if (n < N) s += cnt[n]; }
    sd[t] = s;
    __syncthreads();
    for (int off = 128; off >= 1; off >>= 1) {
        if (t < off) sd[t] += sd[t + off];
        __syncthreads();
    }
    if (t == 0) bsums[blockIdx.x] = sd[0];
}

// Kernel 3b: exclusive scan of block sums in place (NB <= 1024).
__global__ __launch_bounds__(1024) void scan_blocksums(int* __restrict__ bsums, int NB)
{
    __shared__ int sd[1024];
    int t = threadIdx.x;
    int v = (t < NB) ? bsums[t] : 0;
    sd[t] = v;
    __syncthreads();
    for (int off = 1; off < 1024; off <<= 1) {
        int add = (t >= off) ? sd[t - off] : 0;
        __syncthreads();
        sd[t] += add;
        __syncthreads();
    }
    if (t < NB) bsums[t] = sd[t] - v;  // exclusive
}

// Kernel 3c: final rowptr + cursor init.
__global__ __launch_bounds__(256) void scan_final(
    const int* __restrict__ cnt, const int* __restrict__ bsums,
    int* __restrict__ rowptr, int* __restrict__ cursor, int N, int E)
{
    __shared__ int sd[256];
    int t = threadIdx.x;
    int n0 = blockIdx.x * 1024 + t * 4;
    int c[4];
#pragma unroll
    for (int i = 0; i < 4; i++) c[i] = (n0 + i < N) ? cnt[n0 + i] : 0;
    int mysum = c[0] + c[1] + c[2] + c[3];
    sd[t] = mysum;
    __syncthreads();
    for (int off = 1; off < 256; off <<= 1) {
        int add = (t >= off) ? sd[t - off] : 0;
        __syncthreads();
        sd[t] += add;
        __syncthreads();
    }
    int r = bsums[blockIdx.x] + sd[t] - mysum;
#pragma unroll
    for (int i = 0; i < 4; i++) {
        int n = n0 + i;
        if (n < N) { rowptr[n] = r; cursor[n] = r; r += c[i]; }
    }
    if (blockIdx.x == 0 && t == 0) rowptr[N] = E;
}

// Kernel 4 (ranged): scatter edge src ids into dst-sorted buckets.
// Block group g = blockIdx%8 (~XCD g) only fills dst range [lo, lo+len):
// all writes to one col cache line then come from a single XCD, so its L2
// merges the ~16 slot-writes into one line writeback instead of 16.
__global__ __launch_bounds__(256) void edge_fill_r(
    const int* __restrict__ ei, int* __restrict__ cursor,
    int* __restrict__ col, int E, int N)
{
    int g = blockIdx.x & (NR - 1);
    int c = blockIdx.x / NR;
    int q = N / NR, r = N % NR;
    int lo  = g * q + (g < r ? g : r);
    int len = q + (g < r ? 1 : 0);
    const int* dp = ei + (size_t)E;
    int segbase = c * EPB;

    if ((E & 3) == 0) {
#pragma unroll
        for (int it = 0; it < 4; it++) {
            int e0 = segbase + it * 1024 + threadIdx.x * 4;
            if (e0 >= E) continue;
            int4 d4 = *(const int4*)(dp + e0);
            bool a0 = (unsigned)(d4.x - lo) < (unsigned)len;
            bool a1 = (unsigned)(d4.y - lo) < (unsigned)len;
            bool a2 = (unsigned)(d4.z - lo) < (unsigned)len;
            bool a3 = (unsigned)(d4.w - lo) < (unsigned)len;
            if (a0 | a1 | a2 | a3) {
                int4 s4 = *(const int4*)(ei + e0);
                if (a0) { int slot = atomicAdd(&cursor[d4.x], 1); col[slot] = s4.x; }
                if (a1) { int slot = atomicAdd(&cursor[d4.y], 1); col[slot] = s4.y; }
                if (a2) { int slot = atomicAdd(&cursor[d4.z], 1); col[slot] = s4.z; }
                if (a3) { int slot = atomicAdd(&cursor[d4.w], 1); col[slot] = s4.w; }
            }
        }
    } else {
        for (int it = 0; it < 16; it++) {
            int e = segbase + it * 256 + threadIdx.x;
            if (e < E) {
                int d = dp[e];
                if ((unsigned)(d - lo) < (unsigned)len) {
                    int slot = atomicAdd(&cursor[d], 1);
                    col[slot] = ei[e];
                }
            }
        }
    }
}

// Kernel 5: weighted degree via gather; dinv = rsqrt(1 + sum_w).
// 16 lanes per node; lane j handles edges start+j, start+j+16, ...
// Also: (a) materializes per-edge weight w[j] (reused by both conv layers,
// removing their pos gathers); (b) scales xwA row in place by dinv[n]
// (z1 = dinv * (x0@Wg1)), removing the dinv[src] gather from the convs.
__global__ __launch_bounds__(256) void deg_gather(
    const int* __restrict__ rowptr, const int* __restrict__ col,
    const float* __restrict__ pos, float* __restrict__ w,
    float* __restrict__ dinv, float* __restrict__ xw, int N)
{
    int t = threadIdx.x;
    int lane = t & 15;
    int n = blockIdx.x * 16 + (t >> 4);
    if (n >= N) return;
    int start = rowptr[n], end = rowptr[n + 1];
    float px = pos[3 * (size_t)n + 0];
    float py = pos[3 * (size_t)n + 1];
    float pz = pos[3 * (size_t)n + 2];
    float sum = 0.0f;
    for (int j = start + lane; j < end; j += 16) {
        int s = col[j];
        float dx = px - pos[3 * (size_t)s + 0];
        float dy = py - pos[3 * (size_t)s + 1];
        float dz = pz - pos[3 * (size_t)s + 2];
        float d = sqrtf(fmaf(dx, dx, fmaf(dy, dy, dz * dz)));
        w[j] = d;
        sum += d;
    }
#pragma unroll
    for (int off = 8; off >= 1; off >>= 1) sum += __shfl_xor(sum, off, 64);
    float di = rsqrtf(1.0f + sum);
    if (lane == 0) dinv[n] = di;
    xw[(size_t)n * EM + lane] *= di;   // z1 = dinv * xwA (coalesced 64B row)
}

// Kernel 6 (x2): fused GCN-mean layer via gather, on pre-scaled operand
// z[s][c] = dinv[s] * xin[s][c]. Per edge: acc += w[j] * z[src][c].
// Self loop is just z[n][c]. Then x = sp(di*acc/(deg+1) + b).
// If mulW: out = (x @ W) * (scale_out ? di : 1)  (pre-scales next layer's z).
__global__ __launch_bounds__(256) void gather_conv(
    const int* __restrict__ rowptr, const int* __restrict__ col,
    const float* __restrict__ w, const float* __restrict__ dinv,
    const float* __restrict__ z, const float* __restrict__ bconv,
    const float* __restrict__ W, float* __restrict__ xout, int N, int mulW)
{
    __shared__ float sW[EM * EM];
    __shared__ float lx[16][EM + 1];
    int t = threadIdx.x;
    sW[t] = W[t];
    int g = t >> 4, c = t & 15;
    int n = blockIdx.x * 16 + g;

    float x = 0.0f;
    float di = 1.0f;
    if (n < N) {
        int start = rowptr[n], end = rowptr[n + 1];
        di = dinv[n];
        float acc0 = z[(size_t)n * EM + c];   // self loop (pre-scaled)
        float acc1 = 0.0f;
        int j = start;
        for (; j + 1 < end; j += 2) {
            int s0 = col[j], s1 = col[j + 1];
            float w0 = w[j], w1 = w[j + 1];
            acc0 = fmaf(w0, z[(size_t)s0 * EM + c], acc0);
            acc1 = fmaf(w1, z[(size_t)s1 * EM + c], acc1);
        }
        if (j < end)
            acc0 = fmaf(w[j], z[(size_t)col[j] * EM + c], acc0);
        float acc = acc0 + acc1;
        float rc = 1.0f / (float)(end - start + 1);
        x = sp(fmaf(acc * di, rc, bconv[c]));
    }
    __syncthreads();      // sW ready
    lx[g][c] = x;
    __syncthreads();
    if (n < N) {
        if (mulW) {
            float a = 0.0f;
#pragma unroll
            for (int j = 0; j < EM; j++) a = fmaf(lx[g][j], sW[j * EM + c], a);
            xout[(size_t)n * EM + c] = a * di;   // pre-scale layer-2 operand
        } else {
            xout[(size_t)n * EM + c] = x;
        }
    }
}

// Kernel 7: dense heads: y = sp(x2 @ Wp1 + bp1); out = (y @ Wp2 + bp2)/sig.
__global__ __launch_bounds__(256) void node_out(
    const float* __restrict__ W_p1, const float* __restrict__ b_p1,
    const float* __restrict__ W_p2, const float* __restrict__ b_p2,
    const float* __restrict__ sig, const float* __restrict__ x2arr,
    float* __restrict__ out, int N)
{
    __shared__ float sP1[EM * EM];
    __shared__ float sbp1[EM];
    __shared__ float sP2[EM * ND];
    __shared__ float sbp2[ND];
    int t = threadIdx.x;
    sP1[t] = W_p1[t];
    if (t < EM)      sbp1[t] = b_p1[t];
    if (t < EM * ND) sP2[t] = W_p2[t];
    if (t < ND)      sbp2[t] = b_p2[t];
    __syncthreads();

    int n = blockIdx.x * 256 + t;
    if (n >= N) return;

    const float4* xp = (const float4*)(x2arr + (size_t)n * EM);
    float x2[EM];
#pragma unroll
    for (int q = 0; q < 4; q++) {
        float4 xv = xp[q];
        x2[4*q+0] = xv.x; x2[4*q+1] = xv.y; x2[4*q+2] = xv.z; x2[4*q+3] = xv.w;
    }
    float y[EM];
#pragma unroll
    for (int k = 0; k < EM; k++) {
        float a = sbp1[k];
#pragma unroll
        for (int j = 0; j < EM; j++) a = fmaf(x2[j], sP1[j * EM + k], a);
        y[k] = sp(a);
    }
    float rs = 1.0f / sig[n];
#pragma unroll
    for (int ch = 0; ch < ND; ch++) {
        float a = sbp2[ch];
#pragma unroll
        for (int j = 0; j < EM; j++) a = fmaf(y[j], sP2[j * ND + ch], a);
        out[(size_t)n * ND + ch] = a * rs;
    }
}

extern "C" void kernel_launch(void* const* d_in, const int* in_sizes, int n_in,
                              void* d_out, int out_size, void* d_ws, size_t ws_size,
                              hipStream_t stream) {
    const float* pos    = (const float*)d_in[0];
    const float* sig    = (const float*)d_in[1];
    const int*   ei     = (const int*)d_in[2];
    const float* W_init = (const float*)d_in[4];
    const float* b_init = (const float*)d_in[5];
    const float* W_g1   = (const float*)d_in[6];
    const float* b_g1   = (const float*)d_in[7];
    const float* W_g2   = (const float*)d_in[8];
    const float* b_g2   = (const float*)d_in[9];
    const float* W_p1   = (const float*)d_in[10];
    const float* b_p1   = (const float*)d_in[11];
    const float* W_p2   = (const float*)d_in[12];
    const float* b_p2   = (const float*)d_in[13];
    float* out = (float*)d_out;

    int N = in_sizes[0] / ND;
    int E = in_sizes[2] / 2;
    size_t Ns = (size_t)N, Es = (size_t)E;

    // Workspace layout (4B elements):
    // rowptr[N+1] | cnt[N] | col[E] | bsums[1024] | dinv[N] | xwA[16N] | xwB[16N] | w[E]
    // cursor aliases the start of xwB (dead before xwB is first written).
    int* rowptr = (int*)d_ws;
    int* cnt    = rowptr + (Ns + 1);
    int* col    = cnt + Ns;
    int* bsums  = col + Es;
    size_t off  = (Ns + 1) + Ns + Es + 1024;
    off = (off + 3) & ~(size_t)3;
    float* dinv = (float*)d_ws + off;
    size_t offA = off + Ns;
    offA = (offA + 3) & ~(size_t)3;
    float* xwA  = (float*)d_ws + offA;
    float* xwB  = xwA + Ns * EM;
    float* wbuf = xwB + Ns * EM;
    int* cursor = (int*)xwB;

    int nbN = (N + 255) / 256;
    int NBS = (N + 1023) / 1024;   // scan blocks (must be <= 1024)
    int nbG = (N + 15) / 16;       // 16 nodes per 256-thread block
    int nbEr = NR * ((E + EPB - 1) / EPB);  // ranged edge kernels

    node_init<<<nbN, 256, 0, stream>>>(pos, W_init, b_init, W_g1, xwA, cnt, N);
    edge_count_r<<<nbEr, 256, 0, stream>>>(ei, cnt, E, N);
    scan_partial<<<NBS, 256, 0, stream>>>(cnt, bsums, N);
    scan_blocksums<<<1, 1024, 0, stream>>>(bsums, NBS);
    scan_final<<<NBS, 256, 0, stream>>>(cnt, bsums, rowptr, cursor, N, E);
    edge_fill_r<<<nbEr, 256, 0, stream>>>(ei, cursor, col, E, N);
    deg_gather<<<nbG, 256, 0, stream>>>(rowptr, col, pos, wbuf, dinv, xwA, N);
    gather_conv<<<nbG, 256, 0, stream>>>(rowptr, col, wbuf, dinv, xwA, b_g1, W_g2, xwB, N, 1);
    gather_conv<<<nbG, 256, 0, stream>>>(rowptr, col, wbuf, dinv, xwB, b_g2, W_g2, xwA, N, 0);
    node_out<<<nbN, 256, 0, stream>>>(W_p1, b_p1, W_p2, b_p2, sig, xwA, out, N);
}